// Round 4
// baseline (289.133 us; speedup 1.0000x reference)
//
#include <hip/hip_runtime.h>
#include <cstdint>

typedef _Float16 f16x8 __attribute__((ext_vector_type(8)));
typedef _Float16 f16x4 __attribute__((ext_vector_type(4)));
typedef float    f32x4 __attribute__((ext_vector_type(4)));

#define AS1 __attribute__((address_space(1)))
#define AS3 __attribute__((address_space(3)))

__device__ __forceinline__ void load16_lds(const void* g, void* l) {
  __builtin_amdgcn_global_load_lds((AS1 void*)g, (AS3 void*)l, 16, 0, 0);
}

// 128x128-tile K-loop, BK=64 via two BK=32 slabs (scores/pv/oproj).
#define GEMM_PROLOGUE(Ab, lda, Bb, ldb)                                   \
  __shared__ _Float16 lA[2 * 128 * 32];                                   \
  __shared__ _Float16 lB[2 * 128 * 32];                                   \
  int tid = threadIdx.x;                                                  \
  int r0 = tid >> 2;                                                      \
  int c0 = (tid & 3) * 8;                                                 \
  const _Float16* ga0 = Ab + (long long)r0 * lda + c0;                    \
  const _Float16* ga1 = Ab + (long long)(r0 + 64) * lda + c0;             \
  const _Float16* gb0 = Bb + (long long)r0 * ldb + c0;                    \
  const _Float16* gb1 = Bb + (long long)(r0 + 64) * ldb + c0;             \
  _Float16* la0 = lA + tid * 8;                                           \
  _Float16* la1 = lA + 2048 + tid * 8;                                    \
  _Float16* la2 = lA + 4096 + tid * 8;                                    \
  _Float16* la3 = lA + 6144 + tid * 8;                                    \
  _Float16* lb0 = lB + tid * 8;                                           \
  _Float16* lb1 = lB + 2048 + tid * 8;                                    \
  _Float16* lb2 = lB + 4096 + tid * 8;                                    \
  _Float16* lb3 = lB + 6144 + tid * 8;                                    \
  f32x4 acc[4][4] = {};                                                   \
  int lane = tid & 63;                                                    \
  int wv = tid >> 6;                                                      \
  int wm = (wv & 1) * 64, wn = (wv >> 1) * 64;                            \
  int l16 = lane & 15, quad = lane >> 4;                                  \
  const _Float16* raBase = lA + (wm + l16) * 32 + quad * 8;               \
  const _Float16* rbBase = lB + (wn + l16) * 32 + quad * 8;

#define GEMM_KLOOP(lda, ldb, KLEN, SWAP)                                  \
  for (int kb = 0; kb < (KLEN); kb += 64) {                               \
    __syncthreads();                                                      \
    load16_lds(ga0, la0);                                                 \
    load16_lds(ga1, la1);                                                 \
    load16_lds(ga0 + 32, la2);                                            \
    load16_lds(ga1 + 32, la3);                                            \
    load16_lds(gb0, lb0);                                                 \
    load16_lds(gb1, lb1);                                                 \
    load16_lds(gb0 + 32, lb2);                                            \
    load16_lds(gb1 + 32, lb3);                                            \
    ga0 += 64; ga1 += 64; gb0 += 64; gb1 += 64;                           \
    __syncthreads();                                                      \
    _Pragma("unroll")                                                     \
    for (int s = 0; s < 2; s++) {                                         \
      f16x8 af[4], bfr[4];                                                \
      _Pragma("unroll")                                                   \
      for (int i = 0; i < 4; i++)                                         \
        af[i] = *(const f16x8*)(raBase + s * 4096 + i * 512);             \
      _Pragma("unroll")                                                   \
      for (int j = 0; j < 4; j++)                                         \
        bfr[j] = *(const f16x8*)(rbBase + s * 4096 + j * 512);            \
      _Pragma("unroll")                                                   \
      for (int i = 0; i < 4; i++)                                         \
        _Pragma("unroll")                                                 \
        for (int j = 0; j < 4; j++)                                       \
          acc[i][j] = (SWAP)                                              \
            ? __builtin_amdgcn_mfma_f32_16x16x32_f16(bfr[j], af[i], acc[i][j], 0, 0, 0) \
            : __builtin_amdgcn_mfma_f32_16x16x32_f16(af[i], bfr[j], acc[i][j], 0, 0, 0);\
    }                                                                     \
  }

// ---------------- fused fp32 -> fp16 convert for all 5 inputs ----------------
__global__ __launch_bounds__(256) void cvt_all(
    const float* __restrict__ x, const float* __restrict__ wq,
    const float* __restrict__ wk, const float* __restrict__ wv,
    const float* __restrict__ wo,
    _Float16* __restrict__ xh, _Float16* __restrict__ wcat,
    _Float16* __restrict__ woh) {
  long long g = (long long)blockIdx.x * 256 + threadIdx.x;
  const float* in; _Float16* out; long long idx;
  if (g < 2097152)      { in = x;  out = xh;             idx = g; }
  else if (g < 2359296) { in = wq; out = wcat;           idx = g - 2097152; }
  else if (g < 2621440) { in = wk; out = wcat + 1048576; idx = g - 2359296; }
  else if (g < 2883584) { in = wv; out = wcat + 2097152; idx = g - 2621440; }
  else                  { in = wo; out = woh;            idx = g - 2883584; }
  float4 v = ((const float4*)in)[idx];
  f16x4 o;
  o[0] = (_Float16)v.x; o[1] = (_Float16)v.y; o[2] = (_Float16)v.z; o[3] = (_Float16)v.w;
  ((f16x4*)out)[idx] = o;
}

// ---------------- fused QKV projection: 256x256 tile, 8-wave, m201 8-phase ----------------
// (structure verified in R3; see ledger comments)
#define VMW(NLIT) asm volatile("s_waitcnt vmcnt(" #NLIT ")" ::: "memory")

#define A0R 0
#define B0R 16384
#define A1R 32768
#define B1R 49152

#define SGA(reg, u, kc) load16_lds(pA + (u) * 65536 + (kc), shm + (reg) + (u) * 4096 + tid * 8)
#define SGB(reg, u, kc) load16_lds(pB + (u) * 65536 + (kc), shm + (reg) + (u) * 4096 + tid * 8)

#define QPH(ABASE, BBASE, MQ, SWAP, STAGES, WAITS)                         \
  {                                                                        \
    if ((MQ) == 0) {                                                       \
      _Pragma("unroll")                                                    \
      for (int nf = 0; nf < 4; nf++) {                                     \
        int o = (BBASE) + rbw + nf * 1024;                                 \
        bf[nf][0] = *(const f16x8*)(shm + o);                              \
        bf[nf][1] = *(const f16x8*)(shm + (o ^ 32));                       \
      }                                                                    \
    }                                                                      \
    f16x8 af[2][2];                                                        \
    _Pragma("unroll")                                                      \
    for (int mi = 0; mi < 2; mi++) {                                       \
      int o = (ABASE) + raw + ((MQ) * 2 + mi) * 1024;                      \
      af[mi][0] = *(const f16x8*)(shm + o);                                \
      af[mi][1] = *(const f16x8*)(shm + (o ^ 32));                         \
    }                                                                      \
    STAGES                                                                 \
    WAITS                                                                  \
    __builtin_amdgcn_sched_barrier(0);                                     \
    __builtin_amdgcn_s_barrier();                                          \
    asm volatile("s_waitcnt lgkmcnt(0)" ::: "memory");                     \
    __builtin_amdgcn_sched_barrier(0);                                     \
    __builtin_amdgcn_s_setprio(1);                                         \
    _Pragma("unroll")                                                      \
    for (int ks = 0; ks < 2; ks++)                                         \
      _Pragma("unroll")                                                    \
      for (int mi = 0; mi < 2; mi++)                                       \
        _Pragma("unroll")                                                  \
        for (int nf = 0; nf < 4; nf++)                                     \
          acc[(MQ) * 2 + mi][nf] = (SWAP)                                  \
            ? __builtin_amdgcn_mfma_f32_16x16x32_f16(bf[nf][ks], af[mi][ks], acc[(MQ) * 2 + mi][nf], 0, 0, 0) \
            : __builtin_amdgcn_mfma_f32_16x16x32_f16(af[mi][ks], bf[nf][ks], acc[(MQ) * 2 + mi][nf], 0, 0, 0); \
    __builtin_amdgcn_s_setprio(0);                                         \
    __builtin_amdgcn_sched_barrier(0);                                     \
    __builtin_amdgcn_s_barrier();                                          \
  }

#define QKV_SETUP(APTR, BPTR)                                              \
  __shared__ _Float16 shm[65536];                                          \
  int tid = threadIdx.x;                                                   \
  const _Float16* pA = (APTR) + (long long)(tid >> 3) * 1024 +             \
                       ((tid & 7) ^ ((tid >> 3) & 7)) * 8;                 \
  const _Float16* pB = (BPTR) + (long long)(tid >> 3) * 1024 +             \
                       ((tid & 7) ^ ((tid >> 3) & 7)) * 8;                 \
  int lane = tid & 63, wv = tid >> 6;                                      \
  int wr = wv & 1, wc = wv >> 1;                                           \
  int l16 = lane & 15, quad = lane >> 4;                                   \
  int cswz = (quad ^ (l16 & 7)) * 8;                                       \
  int raw = (wr * 128 + l16) * 64 + cswz;                                  \
  int rbw = (wc * 64 + l16) * 64 + cswz;                                   \
  f32x4 acc[8][4] = {};

#define QKV_PRO()                                                          \
  SGB(B0R, 0, 0); SGB(B0R, 1, 0); SGB(B0R, 2, 0); SGB(B0R, 3, 0);          \
  SGA(A0R, 0, 0); SGA(A0R, 1, 0); SGA(A0R, 2, 0); SGA(A0R, 3, 0);          \
  SGB(B1R, 0, 64); SGB(B1R, 1, 64); SGB(B1R, 2, 64); SGB(B1R, 3, 64);      \
  SGA(A1R, 0, 64); SGA(A1R, 2, 64);                                        \
  VMW(6);                                                                  \
  __builtin_amdgcn_s_barrier();

#define QKV_MAIN(SWAP)                                                     \
  _Pragma("unroll 1")                                                      \
  for (int it = 0; it < 7; ++it) {                                         \
    int kb = it * 128;                                                     \
    f16x8 bf[4][2];                                                        \
    QPH(A0R, B0R, 0, SWAP, { SGA(A1R, 1, kb + 64);  SGA(A1R, 3, kb + 64); }, {})  \
    QPH(A0R, B0R, 1, SWAP, { SGB(B0R, 0, kb + 128); SGB(B0R, 1, kb + 128); }, {}) \
    QPH(A0R, B0R, 2, SWAP, { SGB(B0R, 2, kb + 128); SGB(B0R, 3, kb + 128); }, {}) \
    QPH(A0R, B0R, 3, SWAP, { SGA(A0R, 0, kb + 128); SGA(A0R, 2, kb + 128); }, { VMW(6); }) \
    QPH(A1R, B1R, 0, SWAP, { SGA(A0R, 1, kb + 128); SGA(A0R, 3, kb + 128); }, {}) \
    QPH(A1R, B1R, 1, SWAP, { SGB(B1R, 0, kb + 192); SGB(B1R, 1, kb + 192); }, {}) \
    QPH(A1R, B1R, 2, SWAP, { SGB(B1R, 2, kb + 192); SGB(B1R, 3, kb + 192); }, {}) \
    QPH(A1R, B1R, 3, SWAP, { SGA(A1R, 0, kb + 192); SGA(A1R, 2, kb + 192); }, { VMW(6); }) \
  }                                                                        \
  {                                                                        \
    f16x8 bf[4][2];                                                        \
    QPH(A0R, B0R, 0, SWAP, { SGA(A1R, 1, 960); SGA(A1R, 3, 960); }, {})    \
    QPH(A0R, B0R, 1, SWAP, {}, {})                                         \
    QPH(A0R, B0R, 2, SWAP, {}, {})                                         \
    QPH(A0R, B0R, 3, SWAP, {}, { VMW(0); })                                \
    QPH(A1R, B1R, 0, SWAP, {}, {})                                         \
    QPH(A1R, B1R, 1, SWAP, {}, {})                                         \
    QPH(A1R, B1R, 2, SWAP, {}, {})                                         \
    QPH(A1R, B1R, 3, SWAP, {}, {})                                         \
  }

// Q (bx 0..3) / K (bx 4..7): SWAP layout, n-contiguous f16x4 stores
__global__ __launch_bounds__(512, 2) void qkv_qk(
    const _Float16* __restrict__ A, const _Float16* __restrict__ B,
    _Float16* __restrict__ Qh, _Float16* __restrict__ Kh) {
  int bid = blockIdx.x;
  int swz = (bid & 7) * 32 + (bid >> 3);   // 256 % 8 == 0 -> bijective
  int by = swz >> 3, bx = swz & 7;         // by 0..31, bx 0..7
  QKV_SETUP(A + (long long)by * 262144, B + (long long)bx * 262144)
  QKV_PRO()
  QKV_MAIN(1)
  _Float16* C = (bx < 4) ? Qh : Kh;
  int m0 = by * 256 + wr * 128 + l16;
  int n0 = (bx & 3) * 256 + wc * 64 + quad * 4;
  #pragma unroll
  for (int i = 0; i < 8; i++)
    #pragma unroll
    for (int j = 0; j < 4; j++) {
      f16x4 pk;
      #pragma unroll
      for (int r = 0; r < 4; r++) pk[r] = (_Float16)acc[i][j][r];
      *(f16x4*)(C + (long long)(m0 + i * 16) * 1024 + (n0 + j * 16)) = pk;
    }
}

// V: NORMAL layout, transposed store into Vt[b][d][s]
__global__ __launch_bounds__(512, 2) void qkv_v(
    const _Float16* __restrict__ A, const _Float16* __restrict__ B,
    _Float16* __restrict__ Vt) {
  int bid = blockIdx.x;
  int swz = (bid & 7) * 16 + (bid >> 3);   // 128 % 8 == 0 -> bijective
  int by = swz >> 2, bx = swz & 3;         // by 0..31, bx 0..3
  QKV_SETUP(A + (long long)by * 262144, B + (long long)(bx + 8) * 262144)
  QKV_PRO()
  QKV_MAIN(0)
  int d0 = bx * 256 + wc * 64 + l16;
  int mg0 = by * 256 + wr * 128 + quad * 4;
  #pragma unroll
  for (int i = 0; i < 8; i++) {
    long long mg = mg0 + i * 16;
    long long b = mg >> 11;
    long long s = mg & 2047;
    #pragma unroll
    for (int j = 0; j < 4; j++) {
      f16x4 pk;
      #pragma unroll
      for (int r = 0; r < 4; r++) pk[r] = (_Float16)acc[i][j][r];
      *(f16x4*)(Vt + (b << 21) + (long long)(d0 + j * 16) * 2048 + s) = pk;
    }
  }
}

// ---------------- scores GEMM: 128x128 tiles, causal grid 544, fused stats ----------------
// Retiled from 64x128 to 128x128 reusing the verified GEMM macros (2x2 wave
// layout). 544 blocks ~= 512 two-per-CU slots (34KB LDS -> 4 blocks/CU cap).
// SWAP layout: acc[i][j][r] = S[m = wm+16i+l16][n = wn+16j+quad*4+r].
// Stats stay 128-col granular -> normalize_p unchanged.
__global__ __launch_bounds__(256) void scores_gemm(
    const _Float16* __restrict__ Qh, const _Float16* __restrict__ Kh,
    _Float16* __restrict__ S, float2* __restrict__ stats) {
  int L = blockIdx.x;
  int swz = (L & 7) * 68 + (L >> 3);      // 544 = 8*68 -> bijective XCD swizzle
  int bz = swz / 136;
  int t = swz % 136;
  int g = (int)((__builtin_sqrtf(8.0f * t + 1.0f) - 1.0f) * 0.5f);
  while ((g + 1) * (g + 2) / 2 <= t) g++;
  while (g * (g + 1) / 2 > t) g--;
  int by = g;                      // 128-row tile, 0..15
  int bx = t - g * (g + 1) / 2;    // 128-col tile, 0..by
  bool diag = (bx == by);

  const _Float16* Ab = Qh + (long long)bz * 2097152 + (long long)by * 128 * 1024;
  const _Float16* Bb = Kh + (long long)bz * 2097152 + (long long)bx * 128 * 1024;
  GEMM_PROLOGUE(Ab, 1024, Bb, 1024)
  __shared__ float redM[4][64];
  __shared__ float redL[4][64];
  GEMM_KLOOP(1024, 1024, 1024, true)

  int rowBase = by * 128;
  int colBase = bx * 128;

  // per-wave row max over its 64-col span (masked on diagonal tile)
  float mloc[4];
  #pragma unroll
  for (int i = 0; i < 4; i++) {
    int grow = rowBase + wm + 16 * i + l16;
    float mx = -3.0e38f;
    #pragma unroll
    for (int j = 0; j < 4; j++)
      #pragma unroll
      for (int r = 0; r < 4; r++) {
        bool ok = !diag || (colBase + wn + 16 * j + quad * 4 + r <= grow);
        mx = ok ? fmaxf(mx, acc[i][j][r]) : mx;
      }
    mx = fmaxf(mx, __shfl_xor(mx, 16));
    mx = fmaxf(mx, __shfl_xor(mx, 32));
    mloc[i] = mx;
  }
  if (quad == 0) {
    #pragma unroll
    for (int i = 0; i < 4; i++) redM[wv][16 * i + l16] = mloc[i];
  }
  __syncthreads();
  // waves {0,2} cover rows 0..63, {1,3} rows 64..127 (parity = wv&1 = wm/64)
  int par = wv & 1;
  float mfin[4];
  #pragma unroll
  for (int i = 0; i < 4; i++) {
    int rl = 16 * i + l16;
    mfin[i] = fmaxf(redM[par][rl], redM[par + 2][rl]);
  }

  // per-wave sum of exp(s - m_t) (masked)
  float lloc[4];
  #pragma unroll
  for (int i = 0; i < 4; i++) {
    int grow = rowBase + wm + 16 * i + l16;
    float sum = 0.f;
    #pragma unroll
    for (int j = 0; j < 4; j++)
      #pragma unroll
      for (int r = 0; r < 4; r++) {
        bool ok = !diag || (colBase + wn + 16 * j + quad * 4 + r <= grow);
        float e = __expf(acc[i][j][r] - mfin[i]);
        sum += ok ? e : 0.f;
      }
    sum += __shfl_xor(sum, 16);
    sum += __shfl_xor(sum, 32);
    lloc[i] = sum;
  }
  if (quad == 0) {
    #pragma unroll
    for (int i = 0; i < 4; i++) redL[wv][16 * i + l16] = lloc[i];
  }
  __syncthreads();
  // one writer per row: waves 0 (rows 0..63) and 1 (rows 64..127), quad==0
  if (wv < 2 && quad == 0) {
    #pragma unroll
    for (int i = 0; i < 4; i++) {
      int rl = 16 * i + l16;
      float lt = redL[wv][rl] + redL[wv + 2][rl];
      stats[((long long)bz * 2048 + rowBase + wv * 64 + rl) * 16 + bx] =
          make_float2(mfin[i], lt);
    }
  }

  // store u = s - m_t as f16x4 (n-contiguous)
  _Float16* Sb = S + (long long)bz * 4194304;
  #pragma unroll
  for (int i = 0; i < 4; i++) {
    long long grow = rowBase + wm + 16 * i + l16;
    #pragma unroll
    for (int j = 0; j < 4; j++) {
      f16x4 u;
      #pragma unroll
      for (int r = 0; r < 4; r++) u[r] = (_Float16)(acc[i][j][r] - mfin[i]);
      *(f16x4*)(Sb + grow * 2048 + (colBase + wn + 16 * j + quad * 4)) = u;
    }
  }
}

// ---------------- normalize: u -> p in place ----------------
__global__ __launch_bounds__(256) void normalize_p(_Float16* __restrict__ S,
                                                   const float2* __restrict__ stats) {
  int g = blockIdx.x;
  int bz = g >> 11, row = g & 2047;
  int nt = (row >> 7) + 1;
  _Float16* srow = S + ((long long)bz * 2048 + row) * 2048;
  const float2* st = stats + ((long long)bz * 2048 + row) * 16;
  __shared__ float sh_invl;
  __shared__ float shd[16];
  int t = threadIdx.x;
  if (t < 16) {
    float2 p = (t < nt) ? st[t] : make_float2(-3.0e38f, 0.f);
    float m = p.x;
    #pragma unroll
    for (int d = 1; d < 16; d <<= 1) m = fmaxf(m, __shfl_xor(m, d));
    float term = p.y * __expf(p.x - m);
    #pragma unroll
    for (int d = 1; d < 16; d <<= 1) term += __shfl_xor(term, d);
    shd[t] = p.x - m;
    if (t == 0) sh_invl = 1.0f / term;
  }
  __syncthreads();
  float invl = sh_invl;
  int Lp = nt << 7;
  for (int c = t; (c << 3) < Lp; c += 256) {
    float dt = shd[c >> 4];
    f16x8 v = ((f16x8*)srow)[c];
    f16x8 o;
    int col0 = c << 3;
    #pragma unroll
    for (int e = 0; e < 8; e++) {
      float u = (float)v[e];
      float pe = __expf(u + dt) * invl;
      o[e] = (col0 + e <= row) ? (_Float16)pe : (_Float16)0.f;
    }
    ((f16x8*)srow)[c] = o;
  }
}

// ---------------- split-K PV GEMM (XCD-swizzled 1-D grid, BK=64) ----------------
__global__ __launch_bounds__(256) void pv_splitk(
    const _Float16* __restrict__ P,
    const _Float16* __restrict__ Vt,
    float* __restrict__ P0, float* __restrict__ P1,
    _Float16* __restrict__ Oh) {
  int bid = blockIdx.x;
  int xcd = bid & 7;
  int bz = xcd >> 1;
  int idx = bid >> 3;
  int cy = idx >> 2;
  int bx = (xcd & 1) * 4 + (idx & 3);
  int by, c;
  if (cy < 8) { by = cy; c = 0; }
  else { int q = cy - 8; by = 8 + (q >> 1); c = q & 1; }
  int kmax = (by + 1) * 128;
  int k0 = c * 1024;
  int klen = min(kmax, k0 + 1024) - k0;

  const _Float16* Ab = P + (long long)bz * 4194304LL + (long long)by * 128 * 2048 + k0;
  const _Float16* Bb = Vt + (long long)bz * 2097152LL + (long long)bx * 128 * 2048 + k0;
  GEMM_PROLOGUE(Ab, 2048, Bb, 2048)
  GEMM_KLOOP(2048, 2048, klen, true)

  int m0 = by * 128 + wm + l16;
  int n0 = bx * 128 + wn + quad * 4;

  if (c == 0 && by < 8) {
    _Float16* C = Oh + (long long)bz * 2097152LL;
    #pragma unroll
    for (int i = 0; i < 4; i++)
      #pragma unroll
      for (int j = 0; j < 4; j++) {
        f16x4 pk;
        #pragma unroll
        for (int r = 0; r < 4; r++) pk[r] = (_Float16)acc[i][j][r];
        *(f16x4*)(C + (long long)(m0 + i * 16) * 1024 + (n0 + j * 16)) = pk;
      }
  } else if (c == 0) {
    float* C = P0 + (long long)bz * 2097152LL;
    #pragma unroll
    for (int i = 0; i < 4; i++)
      #pragma unroll
      for (int j = 0; j < 4; j++)
        *(f32x4*)(C + (long long)(m0 + i * 16) * 1024 + (n0 + j * 16)) = acc[i][j];
  } else {
    float* C = P1 + (long long)bz * 1048576LL;
    int mr = m0 - 1024;
    #pragma unroll
    for (int i = 0; i < 4; i++)
      #pragma unroll
      for (int j = 0; j < 4; j++)
        *(f32x4*)(C + (long long)(mr + i * 16) * 1024 + (n0 + j * 16)) = acc[i][j];
  }
}

// ---------------- PV reduce, upper 1024 rows only ----------------
__global__ __launch_bounds__(256) void pv_reduce(const float* __restrict__ P0,
                                                 const float* __restrict__ P1,
                                                 _Float16* __restrict__ Oh) {
  int i = blockIdx.x * 256 + threadIdx.x;
  if (i >= 1048576) return;
  int f4 = i;
  int bz = f4 >> 18;
  int loc = f4 & 262143;
  long long p0i = (long long)bz * 524288 + 262144 + loc;
  float4 v = ((const float4*)P0)[p0i];
  float4 w = ((const float4*)P1)[f4];
  v.x += w.x; v.y += w.y; v.z += w.z; v.w += w.w;
  f16x4 o;
  o[0] = (_Float16)v.x; o[1] = (_Float16)v.y; o[2] = (_Float16)v.z; o[3] = (_Float16)v.w;
  ((f16x4*)Oh)[p0i] = o;
}

// ---------------- output projection (+bias, fp32, swapped float4 stores) ----------------
__global__ __launch_bounds__(256) void oproj_gemm(
    const _Float16* __restrict__ A, const _Float16* __restrict__ B,
    float* __restrict__ C, const float* __restrict__ bias) {
  int bx = blockIdx.x, by = blockIdx.y;
  const _Float16* Ab = A + (long long)by * 128 * 1024;
  const _Float16* Bb = B + (long long)bx * 128 * 1024;
  GEMM_PROLOGUE(Ab, 1024, Bb, 1024)
  GEMM_KLOOP(1024, 1024, 1024, true)

  int m0 = by * 128 + wm + l16;
  int n0 = bx * 128 + wn + quad * 4;
  #pragma unroll
  for (int j = 0; j < 4; j++) {
    float4 b4 = *(const float4*)(bias + n0 + j * 16);
    #pragma unroll
    for (int i = 0; i < 4; i++) {
      f32x4 v = acc[i][j];
      v[0] += b4.x; v[1] += b4.y; v[2] += b4.z; v[3] += b4.w;
      *(f32x4*)(C + (long long)(m0 + i * 16) * 1024 + (n0 + j * 16)) = v;
    }
  }
}

// ---------------- workspace layout (bytes) ----------------
// xh   : 0          16,777,216   -> P1 alias during PV
// Wcat : 16777216    6,291,456
// Woh  : 23068672    2,097,152
// Qh   : 25165824   16,777,216   -> P0 alias (with Kh) during PV
// Kh   : 41943040   16,777,216
// Vt   : 58720256   16,777,216
// Oh   : 75497472   16,777,216
// Sb   : 92274688   33,554,432   fp16 u/p [4][2048][2048]
// stats: 125829120   1,048,576   float2 [4][2048][16]
// total: 126,877,696

extern "C" void kernel_launch(void* const* d_in, const int* in_sizes, int n_in,
                              void* d_out, int out_size, void* d_ws, size_t ws_size,
                              hipStream_t stream) {
  const float* x  = (const float*)d_in[0];
  const float* Wq = (const float*)d_in[1];
  const float* Wk = (const float*)d_in[2];
  const float* Wv = (const float*)d_in[3];
  const float* Wo = (const float*)d_in[4];
  const float* bO = (const float*)d_in[5];

  char* ws = (char*)d_ws;
  _Float16* xh   = (_Float16*)(ws + 0);
  _Float16* Wcat = (_Float16*)(ws + 16777216);
  _Float16* Woh  = (_Float16*)(ws + 23068672);
  _Float16* Qh   = (_Float16*)(ws + 25165824);
  _Float16* Kh   = (_Float16*)(ws + 41943040);
  _Float16* Vt   = (_Float16*)(ws + 58720256);
  _Float16* Oh   = (_Float16*)(ws + 75497472);
  _Float16* Sb   = (_Float16*)(ws + 92274688);
  float2*   stats= (float2*)  (ws + 125829120);
  float*    P0   = (float*)   (ws + 25165824);
  float*    P1   = (float*)   (ws + 0);

  dim3 blk(256);

  cvt_all<<<12288, blk, 0, stream>>>(x, Wq, Wk, Wv, Wo, xh, Wcat, Woh);

  // fused Q/K/V projection: 256^2 tiles, 8 waves, m201 8-phase counted-vmcnt
  qkv_qk<<<256, dim3(512), 0, stream>>>(xh, Wcat, Qh, Kh);
  qkv_v<<<128, dim3(512), 0, stream>>>(xh, Wcat, Vt);

  // scores + fused softmax statistics: 128x128 tiles, compact causal grid
  scores_gemm<<<544, blk, 0, stream>>>(Qh, Kh, Sb, stats);

  // combine stats + normalize u -> p in place
  normalize_p<<<8192, blk, 0, stream>>>(Sb, stats);

  // O = P @ Vt^T with split-K
  pv_splitk<<<768, blk, 0, stream>>>(Sb, Vt, P0, P1, Oh);
  pv_reduce<<<4096, blk, 0, stream>>>(P0, P1, Oh);

  // out = O @ Wo^T + b_O
  oproj_gemm<<<dim3(8, 64, 1), blk, 0, stream>>>(Oh, Woh, (float*)d_out, bO);
}

// Round 5
// 275.883 us; speedup vs baseline: 1.0480x; 1.0480x over previous
//
#include <hip/hip_runtime.h>
#include <cstdint>

typedef _Float16 f16x8 __attribute__((ext_vector_type(8)));
typedef _Float16 f16x4 __attribute__((ext_vector_type(4)));
typedef float    f32x4 __attribute__((ext_vector_type(4)));

#define AS1 __attribute__((address_space(1)))
#define AS3 __attribute__((address_space(3)))

__device__ __forceinline__ void load16_lds(const void* g, void* l) {
  __builtin_amdgcn_global_load_lds((AS1 void*)g, (AS3 void*)l, 16, 0, 0);
}

// ---------------- 128x128-tile K-loop, BK=64, conflict-free LDS ----------------
// LDS rows are 64 halfs (128B). Staging: issue = 32 rows x 64 halfs; thread t
// stages row (t>>3), LDS chunk (t&7), GLOBAL chunk (t&7)^(row&7) (pre-swizzled
// source, linear global_load_lds dest). Read: global chunk c of row r lives at
// LDS chunk c^(r&7) -> 64 lanes spread over 8 distinct 16B columns per 8-row
// stripe = bank-conflict-free ds_read_b128 (pattern verified in qkv: R1/R3,
// SQ_LDS_BANK_CONFLICT == 0). Same bytes, same load count, bit-identical MFMA
// operands as the old slab layout.
#define GEMM_PROLOGUE(Ab, lda, Bb, ldb)                                   \
  __shared__ _Float16 lA[128 * 64];                                       \
  __shared__ _Float16 lB[128 * 64];                                       \
  int tid = threadIdx.x;                                                  \
  int srow = tid >> 3;                                                    \
  int gch = ((tid & 7) ^ (srow & 7)) * 8;                                 \
  const _Float16* gA = Ab + (long long)srow * (lda) + gch;                \
  const _Float16* gB = Bb + (long long)srow * (ldb) + gch;                \
  _Float16* lAw = lA + tid * 8;                                           \
  _Float16* lBw = lB + tid * 8;                                           \
  f32x4 acc[4][4] = {};                                                   \
  int lane = tid & 63;                                                    \
  int wv = tid >> 6;                                                      \
  int wm = (wv & 1) * 64, wn = (wv >> 1) * 64;                            \
  int l16 = lane & 15, quad = lane >> 4;                                  \
  int cswz = (quad ^ (l16 & 7)) * 8;                                      \
  int raw = (wm + l16) * 64 + cswz;                                       \
  int rbw = (wn + l16) * 64 + cswz;

#define GEMM_KLOOP(lda, ldb, KLEN, SWAP)                                  \
  for (int kb = 0; kb < (KLEN); kb += 64) {                               \
    __syncthreads();                                                      \
    load16_lds(gA,              lAw);                                     \
    load16_lds(gA + 32 * (lda), lAw + 2048);                              \
    load16_lds(gA + 64 * (lda), lAw + 4096);                              \
    load16_lds(gA + 96 * (lda), lAw + 6144);                              \
    load16_lds(gB,              lBw);                                     \
    load16_lds(gB + 32 * (ldb), lBw + 2048);                              \
    load16_lds(gB + 64 * (ldb), lBw + 4096);                              \
    load16_lds(gB + 96 * (ldb), lBw + 6144);                              \
    gA += 64; gB += 64;                                                   \
    __syncthreads();                                                      \
    _Pragma("unroll")                                                     \
    for (int s = 0; s < 2; s++) {                                         \
      int sx = s * 32;                                                    \
      f16x8 af[4], bfr[4];                                                \
      _Pragma("unroll")                                                   \
      for (int i = 0; i < 4; i++)                                         \
        af[i] = *(const f16x8*)(lA + ((raw + i * 1024) ^ sx));            \
      _Pragma("unroll")                                                   \
      for (int j = 0; j < 4; j++)                                         \
        bfr[j] = *(const f16x8*)(lB + ((rbw + j * 1024) ^ sx));           \
      _Pragma("unroll")                                                   \
      for (int i = 0; i < 4; i++)                                         \
        _Pragma("unroll")                                                 \
        for (int j = 0; j < 4; j++)                                       \
          acc[i][j] = (SWAP)                                              \
            ? __builtin_amdgcn_mfma_f32_16x16x32_f16(bfr[j], af[i], acc[i][j], 0, 0, 0) \
            : __builtin_amdgcn_mfma_f32_16x16x32_f16(af[i], bfr[j], acc[i][j], 0, 0, 0);\
    }                                                                     \
  }

// ---------------- fused fp32 -> fp16 convert for all 5 inputs ----------------
__global__ __launch_bounds__(256) void cvt_all(
    const float* __restrict__ x, const float* __restrict__ wq,
    const float* __restrict__ wk, const float* __restrict__ wv,
    const float* __restrict__ wo,
    _Float16* __restrict__ xh, _Float16* __restrict__ wcat,
    _Float16* __restrict__ woh) {
  long long g = (long long)blockIdx.x * 256 + threadIdx.x;
  const float* in; _Float16* out; long long idx;
  if (g < 2097152)      { in = x;  out = xh;             idx = g; }
  else if (g < 2359296) { in = wq; out = wcat;           idx = g - 2097152; }
  else if (g < 2621440) { in = wk; out = wcat + 1048576; idx = g - 2359296; }
  else if (g < 2883584) { in = wv; out = wcat + 2097152; idx = g - 2621440; }
  else                  { in = wo; out = woh;            idx = g - 2883584; }
  float4 v = ((const float4*)in)[idx];
  f16x4 o;
  o[0] = (_Float16)v.x; o[1] = (_Float16)v.y; o[2] = (_Float16)v.z; o[3] = (_Float16)v.w;
  ((f16x4*)out)[idx] = o;
}

// ---------------- fused QKV projection: 256x256 tile, 8-wave, m201 8-phase ----------------
// (structure verified in R3; see ledger comments there)
#define VMW(NLIT) asm volatile("s_waitcnt vmcnt(" #NLIT ")" ::: "memory")

#define A0R 0
#define B0R 16384
#define A1R 32768
#define B1R 49152

#define SGA(reg, u, kc) load16_lds(pA + (u) * 65536 + (kc), shm + (reg) + (u) * 4096 + tid * 8)
#define SGB(reg, u, kc) load16_lds(pB + (u) * 65536 + (kc), shm + (reg) + (u) * 4096 + tid * 8)

#define QPH(ABASE, BBASE, MQ, SWAP, STAGES, WAITS)                         \
  {                                                                        \
    if ((MQ) == 0) {                                                       \
      _Pragma("unroll")                                                    \
      for (int nf = 0; nf < 4; nf++) {                                     \
        int o = (BBASE) + rbw + nf * 1024;                                 \
        bf[nf][0] = *(const f16x8*)(shm + o);                              \
        bf[nf][1] = *(const f16x8*)(shm + (o ^ 32));                       \
      }                                                                    \
    }                                                                      \
    f16x8 af[2][2];                                                        \
    _Pragma("unroll")                                                      \
    for (int mi = 0; mi < 2; mi++) {                                       \
      int o = (ABASE) + raw + ((MQ) * 2 + mi) * 1024;                      \
      af[mi][0] = *(const f16x8*)(shm + o);                                \
      af[mi][1] = *(const f16x8*)(shm + (o ^ 32));                         \
    }                                                                      \
    STAGES                                                                 \
    WAITS                                                                  \
    __builtin_amdgcn_sched_barrier(0);                                     \
    __builtin_amdgcn_s_barrier();                                          \
    asm volatile("s_waitcnt lgkmcnt(0)" ::: "memory");                     \
    __builtin_amdgcn_sched_barrier(0);                                     \
    __builtin_amdgcn_s_setprio(1);                                         \
    _Pragma("unroll")                                                      \
    for (int ks = 0; ks < 2; ks++)                                         \
      _Pragma("unroll")                                                    \
      for (int mi = 0; mi < 2; mi++)                                       \
        _Pragma("unroll")                                                  \
        for (int nf = 0; nf < 4; nf++)                                     \
          acc[(MQ) * 2 + mi][nf] = (SWAP)                                  \
            ? __builtin_amdgcn_mfma_f32_16x16x32_f16(bf[nf][ks], af[mi][ks], acc[(MQ) * 2 + mi][nf], 0, 0, 0) \
            : __builtin_amdgcn_mfma_f32_16x16x32_f16(af[mi][ks], bf[nf][ks], acc[(MQ) * 2 + mi][nf], 0, 0, 0); \
    __builtin_amdgcn_s_setprio(0);                                         \
    __builtin_amdgcn_sched_barrier(0);                                     \
    __builtin_amdgcn_s_barrier();                                          \
  }

#define QKV_SETUP(APTR, BPTR)                                              \
  __shared__ _Float16 shm[65536];                                          \
  int tid = threadIdx.x;                                                   \
  const _Float16* pA = (APTR) + (long long)(tid >> 3) * 1024 +             \
                       ((tid & 7) ^ ((tid >> 3) & 7)) * 8;                 \
  const _Float16* pB = (BPTR) + (long long)(tid >> 3) * 1024 +             \
                       ((tid & 7) ^ ((tid >> 3) & 7)) * 8;                 \
  int lane = tid & 63, wv = tid >> 6;                                      \
  int wr = wv & 1, wc = wv >> 1;                                           \
  int l16 = lane & 15, quad = lane >> 4;                                   \
  int cswz = (quad ^ (l16 & 7)) * 8;                                       \
  int raw = (wr * 128 + l16) * 64 + cswz;                                  \
  int rbw = (wc * 64 + l16) * 64 + cswz;                                   \
  f32x4 acc[8][4] = {};

#define QKV_PRO()                                                          \
  SGB(B0R, 0, 0); SGB(B0R, 1, 0); SGB(B0R, 2, 0); SGB(B0R, 3, 0);          \
  SGA(A0R, 0, 0); SGA(A0R, 1, 0); SGA(A0R, 2, 0); SGA(A0R, 3, 0);          \
  SGB(B1R, 0, 64); SGB(B1R, 1, 64); SGB(B1R, 2, 64); SGB(B1R, 3, 64);      \
  SGA(A1R, 0, 64); SGA(A1R, 2, 64);                                        \
  VMW(6);                                                                  \
  __builtin_amdgcn_s_barrier();

#define QKV_MAIN(SWAP)                                                     \
  _Pragma("unroll 1")                                                      \
  for (int it = 0; it < 7; ++it) {                                         \
    int kb = it * 128;                                                     \
    f16x8 bf[4][2];                                                        \
    QPH(A0R, B0R, 0, SWAP, { SGA(A1R, 1, kb + 64);  SGA(A1R, 3, kb + 64); }, {})  \
    QPH(A0R, B0R, 1, SWAP, { SGB(B0R, 0, kb + 128); SGB(B0R, 1, kb + 128); }, {}) \
    QPH(A0R, B0R, 2, SWAP, { SGB(B0R, 2, kb + 128); SGB(B0R, 3, kb + 128); }, {}) \
    QPH(A0R, B0R, 3, SWAP, { SGA(A0R, 0, kb + 128); SGA(A0R, 2, kb + 128); }, { VMW(6); }) \
    QPH(A1R, B1R, 0, SWAP, { SGA(A0R, 1, kb + 128); SGA(A0R, 3, kb + 128); }, {}) \
    QPH(A1R, B1R, 1, SWAP, { SGB(B1R, 0, kb + 192); SGB(B1R, 1, kb + 192); }, {}) \
    QPH(A1R, B1R, 2, SWAP, { SGB(B1R, 2, kb + 192); SGB(B1R, 3, kb + 192); }, {}) \
    QPH(A1R, B1R, 3, SWAP, { SGA(A1R, 0, kb + 192); SGA(A1R, 2, kb + 192); }, { VMW(6); }) \
  }                                                                        \
  {                                                                        \
    f16x8 bf[4][2];                                                        \
    QPH(A0R, B0R, 0, SWAP, { SGA(A1R, 1, 960); SGA(A1R, 3, 960); }, {})    \
    QPH(A0R, B0R, 1, SWAP, {}, {})                                         \
    QPH(A0R, B0R, 2, SWAP, {}, {})                                         \
    QPH(A0R, B0R, 3, SWAP, {}, { VMW(0); })                                \
    QPH(A1R, B1R, 0, SWAP, {}, {})                                         \
    QPH(A1R, B1R, 1, SWAP, {}, {})                                         \
    QPH(A1R, B1R, 2, SWAP, {}, {})                                         \
    QPH(A1R, B1R, 3, SWAP, {}, {})                                         \
  }

// Q (bx 0..3) / K (bx 4..7): SWAP layout, n-contiguous f16x4 stores
__global__ __launch_bounds__(512, 2) void qkv_qk(
    const _Float16* __restrict__ A, const _Float16* __restrict__ B,
    _Float16* __restrict__ Qh, _Float16* __restrict__ Kh) {
  int bid = blockIdx.x;
  int swz = (bid & 7) * 32 + (bid >> 3);   // 256 % 8 == 0 -> bijective
  int by = swz >> 3, bx = swz & 7;         // by 0..31, bx 0..7
  QKV_SETUP(A + (long long)by * 262144, B + (long long)bx * 262144)
  QKV_PRO()
  QKV_MAIN(1)
  _Float16* C = (bx < 4) ? Qh : Kh;
  int m0 = by * 256 + wr * 128 + l16;
  int n0 = (bx & 3) * 256 + wc * 64 + quad * 4;
  #pragma unroll
  for (int i = 0; i < 8; i++)
    #pragma unroll
    for (int j = 0; j < 4; j++) {
      f16x4 pk;
      #pragma unroll
      for (int r = 0; r < 4; r++) pk[r] = (_Float16)acc[i][j][r];
      *(f16x4*)(C + (long long)(m0 + i * 16) * 1024 + (n0 + j * 16)) = pk;
    }
}

// V: NORMAL layout, transposed store into Vt[b][d][s]
__global__ __launch_bounds__(512, 2) void qkv_v(
    const _Float16* __restrict__ A, const _Float16* __restrict__ B,
    _Float16* __restrict__ Vt) {
  int bid = blockIdx.x;
  int swz = (bid & 7) * 16 + (bid >> 3);   // 128 % 8 == 0 -> bijective
  int by = swz >> 2, bx = swz & 3;         // by 0..31, bx 0..3
  QKV_SETUP(A + (long long)by * 262144, B + (long long)(bx + 8) * 262144)
  QKV_PRO()
  QKV_MAIN(0)
  int d0 = bx * 256 + wc * 64 + l16;
  int mg0 = by * 256 + wr * 128 + quad * 4;
  #pragma unroll
  for (int i = 0; i < 8; i++) {
    long long mg = mg0 + i * 16;
    long long b = mg >> 11;
    long long s = mg & 2047;
    #pragma unroll
    for (int j = 0; j < 4; j++) {
      f16x4 pk;
      #pragma unroll
      for (int r = 0; r < 4; r++) pk[r] = (_Float16)acc[i][j][r];
      *(f16x4*)(Vt + (b << 21) + (long long)(d0 + j * 16) * 2048 + s) = pk;
    }
  }
}

// ---------------- scores GEMM, 64x128 tiles, compact causal grid (R3 structure),
// with conflict-free 64-half-row LDS core ----------------
__global__ __launch_bounds__(256) void scores_gemm(
    const _Float16* __restrict__ Qh, const _Float16* __restrict__ Kh,
    _Float16* __restrict__ S, float2* __restrict__ stats) {
  int L = blockIdx.x;
  int xcd = L & 7;
  int bz = xcd >> 1;
  int t = (L >> 3) + (xcd & 1) * 136;
  int g = (int)((__builtin_sqrtf(4.0f * t + 1.0f) - 1.0f) * 0.5f);
  while ((g + 1) * (g + 2) <= t) g++;
  while (g * (g + 1) > t) g--;
  int rem = t - g * (g + 1);
  int by = 2 * g + (rem > g ? 1 : 0);         // 64-row tile index, 0..31
  int bxt = (rem > g) ? rem - (g + 1) : rem;  // 128-col tile index, 0..g
  bool diag = (bxt == g);

  const _Float16* Ab = Qh + (long long)bz * 2097152 + (long long)by * 64 * 1024;
  const _Float16* Bb = Kh + (long long)bz * 2097152 + (long long)bxt * 128 * 1024;

  __shared__ _Float16 lA[64 * 64];
  __shared__ _Float16 lB[128 * 64];
  __shared__ float redM[4][64];
  __shared__ float redL[4][64];

  int tid = threadIdx.x;
  int srow = tid >> 3;
  int gch = ((tid & 7) ^ (srow & 7)) * 8;
  const _Float16* gA = Ab + (long long)srow * 1024 + gch;
  const _Float16* gB = Bb + (long long)srow * 1024 + gch;
  _Float16* lAw = lA + tid * 8;
  _Float16* lBw = lB + tid * 8;

  f32x4 acc[4][2] = {};
  int lane = tid & 63;
  int wv = tid >> 6;
  int wn = wv * 32;
  int l16 = lane & 15, quad = lane >> 4;
  int cswz = (quad ^ (l16 & 7)) * 8;
  int raw = l16 * 64 + cswz;
  int rbw = (wn + l16) * 64 + cswz;

  for (int kb = 0; kb < 1024; kb += 64) {
    __syncthreads();
    load16_lds(gA,             lAw);
    load16_lds(gA + 32 * 1024, lAw + 2048);
    load16_lds(gB,             lBw);
    load16_lds(gB + 32 * 1024, lBw + 2048);
    load16_lds(gB + 64 * 1024, lBw + 4096);
    load16_lds(gB + 96 * 1024, lBw + 6144);
    gA += 64; gB += 64;
    __syncthreads();
    #pragma unroll
    for (int s = 0; s < 2; s++) {
      int sx = s * 32;
      f16x8 af[4], bfr[2];
      #pragma unroll
      for (int i = 0; i < 4; i++)
        af[i] = *(const f16x8*)(lA + ((raw + i * 1024) ^ sx));
      #pragma unroll
      for (int j = 0; j < 2; j++)
        bfr[j] = *(const f16x8*)(lB + ((rbw + j * 1024) ^ sx));
      #pragma unroll
      for (int i = 0; i < 4; i++)
        #pragma unroll
        for (int j = 0; j < 2; j++)
          acc[i][j] = __builtin_amdgcn_mfma_f32_16x16x32_f16(bfr[j], af[i], acc[i][j], 0, 0, 0);
    }
  }

  int rowBase = by * 64;
  int colBase = bxt * 128;

  // per-wave row max (masked on diagonal tile)
  float mloc[4];
  #pragma unroll
  for (int i = 0; i < 4; i++) {
    int grow = rowBase + 16 * i + l16;
    float mx = -3.0e38f;
    #pragma unroll
    for (int j = 0; j < 2; j++)
      #pragma unroll
      for (int r = 0; r < 4; r++) {
        bool ok = !diag || (colBase + wn + 16 * j + quad * 4 + r <= grow);
        mx = ok ? fmaxf(mx, acc[i][j][r]) : mx;
      }
    mx = fmaxf(mx, __shfl_xor(mx, 16));
    mx = fmaxf(mx, __shfl_xor(mx, 32));
    mloc[i] = mx;
  }
  if (quad == 0) {
    #pragma unroll
    for (int i = 0; i < 4; i++) redM[wv][16 * i + l16] = mloc[i];
  }
  __syncthreads();
  float mfin[4];
  #pragma unroll
  for (int i = 0; i < 4; i++) {
    int rl = 16 * i + l16;
    mfin[i] = fmaxf(fmaxf(redM[0][rl], redM[1][rl]), fmaxf(redM[2][rl], redM[3][rl]));
  }

  // per-wave sum of exp(s - m_t) (masked)
  float lloc[4];
  #pragma unroll
  for (int i = 0; i < 4; i++) {
    int grow = rowBase + 16 * i + l16;
    float sum = 0.f;
    #pragma unroll
    for (int j = 0; j < 2; j++)
      #pragma unroll
      for (int r = 0; r < 4; r++) {
        bool ok = !diag || (colBase + wn + 16 * j + quad * 4 + r <= grow);
        float e = __expf(acc[i][j][r] - mfin[i]);
        sum += ok ? e : 0.f;
      }
    sum += __shfl_xor(sum, 16);
    sum += __shfl_xor(sum, 32);
    lloc[i] = sum;
  }
  if (quad == 0) {
    #pragma unroll
    for (int i = 0; i < 4; i++) redL[wv][16 * i + l16] = lloc[i];
  }
  __syncthreads();
  if (wv == 0 && quad == 0) {
    #pragma unroll
    for (int i = 0; i < 4; i++) {
      int rl = 16 * i + l16;
      float lt = redL[0][rl] + redL[1][rl] + redL[2][rl] + redL[3][rl];
      stats[((long long)bz * 2048 + rowBase + rl) * 16 + bxt] =
          make_float2(mfin[i], lt);
    }
  }

  // store u = s - m_t as f16x4 (n-contiguous)
  _Float16* Sb = S + (long long)bz * 4194304;
  #pragma unroll
  for (int i = 0; i < 4; i++) {
    long long grow = rowBase + 16 * i + l16;
    #pragma unroll
    for (int j = 0; j < 2; j++) {
      f16x4 u;
      #pragma unroll
      for (int r = 0; r < 4; r++) u[r] = (_Float16)(acc[i][j][r] - mfin[i]);
      *(f16x4*)(Sb + grow * 2048 + (colBase + wn + 16 * j + quad * 4)) = u;
    }
  }
}

// ---------------- normalize: u -> p in place ----------------
__global__ __launch_bounds__(256) void normalize_p(_Float16* __restrict__ S,
                                                   const float2* __restrict__ stats) {
  int g = blockIdx.x;
  int bz = g >> 11, row = g & 2047;
  int nt = (row >> 7) + 1;
  _Float16* srow = S + ((long long)bz * 2048 + row) * 2048;
  const float2* st = stats + ((long long)bz * 2048 + row) * 16;
  __shared__ float sh_invl;
  __shared__ float shd[16];
  int t = threadIdx.x;
  if (t < 16) {
    float2 p = (t < nt) ? st[t] : make_float2(-3.0e38f, 0.f);
    float m = p.x;
    #pragma unroll
    for (int d = 1; d < 16; d <<= 1) m = fmaxf(m, __shfl_xor(m, d));
    float term = p.y * __expf(p.x - m);
    #pragma unroll
    for (int d = 1; d < 16; d <<= 1) term += __shfl_xor(term, d);
    shd[t] = p.x - m;
    if (t == 0) sh_invl = 1.0f / term;
  }
  __syncthreads();
  float invl = sh_invl;
  int Lp = nt << 7;
  for (int c = t; (c << 3) < Lp; c += 256) {
    float dt = shd[c >> 4];
    f16x8 v = ((f16x8*)srow)[c];
    f16x8 o;
    int col0 = c << 3;
    #pragma unroll
    for (int e = 0; e < 8; e++) {
      float u = (float)v[e];
      float pe = __expf(u + dt) * invl;
      o[e] = (col0 + e <= row) ? (_Float16)pe : (_Float16)0.f;
    }
    ((f16x8*)srow)[c] = o;
  }
}

// ---------------- split-K PV GEMM (XCD-swizzled 1-D grid, BK=64) ----------------
__global__ __launch_bounds__(256) void pv_splitk(
    const _Float16* __restrict__ P,
    const _Float16* __restrict__ Vt,
    float* __restrict__ P0, float* __restrict__ P1,
    _Float16* __restrict__ Oh) {
  int bid = blockIdx.x;
  int xcd = bid & 7;
  int bz = xcd >> 1;
  int idx = bid >> 3;
  int cy = idx >> 2;
  int bx = (xcd & 1) * 4 + (idx & 3);
  int by, c;
  if (cy < 8) { by = cy; c = 0; }
  else { int q = cy - 8; by = 8 + (q >> 1); c = q & 1; }
  int kmax = (by + 1) * 128;
  int k0 = c * 1024;
  int klen = min(kmax, k0 + 1024) - k0;

  const _Float16* Ab = P + (long long)bz * 4194304LL + (long long)by * 128 * 2048 + k0;
  const _Float16* Bb = Vt + (long long)bz * 2097152LL + (long long)bx * 128 * 2048 + k0;
  GEMM_PROLOGUE(Ab, 2048, Bb, 2048)
  GEMM_KLOOP(2048, 2048, klen, true)

  int m0 = by * 128 + wm + l16;
  int n0 = bx * 128 + wn + quad * 4;

  if (c == 0 && by < 8) {
    _Float16* C = Oh + (long long)bz * 2097152LL;
    #pragma unroll
    for (int i = 0; i < 4; i++)
      #pragma unroll
      for (int j = 0; j < 4; j++) {
        f16x4 pk;
        #pragma unroll
        for (int r = 0; r < 4; r++) pk[r] = (_Float16)acc[i][j][r];
        *(f16x4*)(C + (long long)(m0 + i * 16) * 1024 + (n0 + j * 16)) = pk;
      }
  } else if (c == 0) {
    float* C = P0 + (long long)bz * 2097152LL;
    #pragma unroll
    for (int i = 0; i < 4; i++)
      #pragma unroll
      for (int j = 0; j < 4; j++)
        *(f32x4*)(C + (long long)(m0 + i * 16) * 1024 + (n0 + j * 16)) = acc[i][j];
  } else {
    float* C = P1 + (long long)bz * 1048576LL;
    int mr = m0 - 1024;
    #pragma unroll
    for (int i = 0; i < 4; i++)
      #pragma unroll
      for (int j = 0; j < 4; j++)
        *(f32x4*)(C + (long long)(mr + i * 16) * 1024 + (n0 + j * 16)) = acc[i][j];
  }
}

// ---------------- PV reduce, upper 1024 rows only ----------------
__global__ __launch_bounds__(256) void pv_reduce(const float* __restrict__ P0,
                                                 const float* __restrict__ P1,
                                                 _Float16* __restrict__ Oh) {
  int i = blockIdx.x * 256 + threadIdx.x;
  if (i >= 1048576) return;
  int f4 = i;
  int bz = f4 >> 18;
  int loc = f4 & 262143;
  long long p0i = (long long)bz * 524288 + 262144 + loc;
  float4 v = ((const float4*)P0)[p0i];
  float4 w = ((const float4*)P1)[f4];
  v.x += w.x; v.y += w.y; v.z += w.z; v.w += w.w;
  f16x4 o;
  o[0] = (_Float16)v.x; o[1] = (_Float16)v.y; o[2] = (_Float16)v.z; o[3] = (_Float16)v.w;
  ((f16x4*)Oh)[p0i] = o;
}

// ---------------- output projection (+bias, fp32, swapped float4 stores) ----------------
__global__ __launch_bounds__(256) void oproj_gemm(
    const _Float16* __restrict__ A, const _Float16* __restrict__ B,
    float* __restrict__ C, const float* __restrict__ bias) {
  int bx = blockIdx.x, by = blockIdx.y;
  const _Float16* Ab = A + (long long)by * 128 * 1024;
  const _Float16* Bb = B + (long long)bx * 128 * 1024;
  GEMM_PROLOGUE(Ab, 1024, Bb, 1024)
  GEMM_KLOOP(1024, 1024, 1024, true)

  int m0 = by * 128 + wm + l16;
  int n0 = bx * 128 + wn + quad * 4;
  #pragma unroll
  for (int j = 0; j < 4; j++) {
    float4 b4 = *(const float4*)(bias + n0 + j * 16);
    #pragma unroll
    for (int i = 0; i < 4; i++) {
      f32x4 v = acc[i][j];
      v[0] += b4.x; v[1] += b4.y; v[2] += b4.z; v[3] += b4.w;
      *(f32x4*)(C + (long long)(m0 + i * 16) * 1024 + (n0 + j * 16)) = v;
    }
  }
}

// ---------------- workspace layout (bytes) ----------------
// xh   : 0          16,777,216   -> P1 alias during PV
// Wcat : 16777216    6,291,456
// Woh  : 23068672    2,097,152
// Qh   : 25165824   16,777,216   -> P0 alias (with Kh) during PV
// Kh   : 41943040   16,777,216
// Vt   : 58720256   16,777,216
// Oh   : 75497472   16,777,216
// Sb   : 92274688   33,554,432   fp16 u/p [4][2048][2048]
// stats: 125829120   1,048,576   float2 [4][2048][16]
// total: 126,877,696

extern "C" void kernel_launch(void* const* d_in, const int* in_sizes, int n_in,
                              void* d_out, int out_size, void* d_ws, size_t ws_size,
                              hipStream_t stream) {
  const float* x  = (const float*)d_in[0];
  const float* Wq = (const float*)d_in[1];
  const float* Wk = (const float*)d_in[2];
  const float* Wv = (const float*)d_in[3];
  const float* Wo = (const float*)d_in[4];
  const float* bO = (const float*)d_in[5];

  char* ws = (char*)d_ws;
  _Float16* xh   = (_Float16*)(ws + 0);
  _Float16* Wcat = (_Float16*)(ws + 16777216);
  _Float16* Woh  = (_Float16*)(ws + 23068672);
  _Float16* Qh   = (_Float16*)(ws + 25165824);
  _Float16* Kh   = (_Float16*)(ws + 41943040);
  _Float16* Vt   = (_Float16*)(ws + 58720256);
  _Float16* Oh   = (_Float16*)(ws + 75497472);
  _Float16* Sb   = (_Float16*)(ws + 92274688);
  float2*   stats= (float2*)  (ws + 125829120);
  float*    P0   = (float*)   (ws + 25165824);
  float*    P1   = (float*)   (ws + 0);

  dim3 blk(256);

  cvt_all<<<12288, blk, 0, stream>>>(x, Wq, Wk, Wv, Wo, xh, Wcat, Woh);

  // fused Q/K/V projection: 256^2 tiles, 8 waves, m201 8-phase counted-vmcnt
  qkv_qk<<<256, dim3(512), 0, stream>>>(xh, Wcat, Qh, Kh);
  qkv_v<<<128, dim3(512), 0, stream>>>(xh, Wcat, Vt);

  // scores + fused softmax statistics: 64x128 tiles, compact causal grid
  scores_gemm<<<1088, blk, 0, stream>>>(Qh, Kh, Sb, stats);

  // combine stats + normalize u -> p in place
  normalize_p<<<8192, blk, 0, stream>>>(Sb, stats);

  // O = P @ Vt^T with split-K
  pv_splitk<<<768, blk, 0, stream>>>(Sb, Vt, P0, P1, Oh);
  pv_reduce<<<4096, blk, 0, stream>>>(P0, P1, Oh);

  // out = O @ Wo^T + b_O
  oproj_gemm<<<dim3(8, 64, 1), blk, 0, stream>>>(Oh, Woh, (float*)d_out, bO);
}